// Round 10
// baseline (204.260 us; speedup 1.0000x reference)
//
#include <hip/hip_runtime.h>
#include <hip/hip_bf16.h>

// DecorrelatedBatchNorm1d (ZCA whitening), B=65536, F=512, fp32 in/out.
// Pipeline:
//   K0 k_zero:     zero S + colsum + tacc (custom fill)
//   K1 k_prep3:    xbT = bf16(x)^T (d_out overlay) + xb = bf16(x) row-major (big ws)
//                  + colsum (fp32 LDS-tile transpose; coalesced 256B/feat writes)
//   K2 k_cov:      S = xbT * xbT^T upper-triangle (bf16 MFMA, split-K, atomics)
//   K3 k_finalize: mean, E = S/(B-1) corrected - I + eps
//   K4 k_poly s0:  E2 = E@E; G = c3*E + c4*E2        (deg-4 Taylor of (I+E)^-1/2)
//   K5 k_poly s1:  W = I + c1*E + c2*E2 + E2@G -> Wb; tacc = mean^T W
//   K6 k_out_b:    out = (xb@W - tacc)*weight + bias  (pure bf16 MFMA GEMM via
//                   global_load_lds; nontemporal out)   [big ws]
//      k_out_f:    same from fp32 x (reg-staged A)      [small-ws fallback]

#define F 512
#define LDT 65536

typedef unsigned short u16;
using bf16x8 = __attribute__((ext_vector_type(8))) short;
using f32x4  = __attribute__((ext_vector_type(4))) float;

// ---- workspace layout (bytes) ----
#define WS_S      0u
#define WS_COLSUM 1048576u
#define WS_TACC   1050624u
#define WS_MEAN   1052672u
#define WS_E      1054720u
#define WS_E2     (WS_E   + 1048576u)
#define WS_EB     (WS_E2  + 1048576u)
#define WS_E2B    (WS_EB  + 524288u)
#define WS_GB     (WS_E2B + 524288u)
#define WS_WB     (WS_GB  + 524288u)
#define WS_XB     (WS_WB  + 524288u)
#define WS_NEED_BIG (WS_XB + 67108864u)

__device__ __forceinline__ u16 f2bf(float x) {
  union { float f; unsigned u; } v; v.f = x;
  return (u16)((v.u + 0x7fffu + ((v.u >> 16) & 1u)) >> 16);
}

__device__ __forceinline__ void async_cp16(const void* g, void* l) {
  __builtin_amdgcn_global_load_lds(
      (const __attribute__((address_space(1))) unsigned int*)g,
      (__attribute__((address_space(3))) unsigned int*)l, 16, 0, 0);
}

// ---- [128 rows][64 k] bf16 tile staging ----
// LDS dest linear; source pre-swizzled: LDS row r chunk c holds global chunk c^(r&7).
__device__ __forceinline__ void stage_tile(u16* dst, const u16* src, size_t stride, int t) {
#pragma unroll
  for (int q = 0; q < 4; ++q) {
    int idx = q * 256 + t;
    int c = idx >> 3, ko = idx & 7;
    async_cp16(src + (size_t)c * stride + (size_t)((ko ^ (c & 7)) << 3), dst + idx * 8);
  }
}

__device__ __forceinline__ void stage512(u16* dst, const u16* src, size_t stride, int t) {
#pragma unroll
  for (int q = 0; q < 2; ++q) {
    int idx = q * 512 + t;
    int c = idx >> 3, ko = idx & 7;
    async_cp16(src + (size_t)c * stride + (size_t)((ko ^ (c & 7)) << 3), dst + idx * 8);
  }
}

__device__ __forceinline__ void stage64(u16* dst, const u16* src, size_t stride, int t) {
#pragma unroll
  for (int q = 0; q < 2; ++q) {
    int idx = q * 256 + t;
    int r = idx >> 3, ko = idx & 7;
    async_cp16(src + (size_t)r * stride + (size_t)((ko ^ (r & 7)) << 3), dst + idx * 8);
  }
}

// 128x128 tile step, 4 waves (k_cov)
__device__ __forceinline__ void mm_step(const u16* As, const u16* Bs, int wr, int wc,
                                        int l, f32x4 acc[4][4]) {
#pragma unroll
  for (int kh = 0; kh < 2; ++kh) {
    bf16x8 a[4], b[4];
#pragma unroll
    for (int m = 0; m < 4; ++m) {
      int row = wr * 64 + m * 16 + (l & 15);
      int ch = (kh * 4 + (l >> 4)) ^ (row & 7);
      a[m] = *(const bf16x8*)(As + row * 64 + ch * 8);
    }
#pragma unroll
    for (int n = 0; n < 4; ++n) {
      int row = wc * 64 + n * 16 + (l & 15);
      int ch = (kh * 4 + (l >> 4)) ^ (row & 7);
      b[n] = *(const bf16x8*)(Bs + row * 64 + ch * 8);
    }
#pragma unroll
    for (int m = 0; m < 4; ++m)
#pragma unroll
      for (int n = 0; n < 4; ++n)
        acc[m][n] = __builtin_amdgcn_mfma_f32_16x16x32_bf16(a[m], b[n], acc[m][n], 0, 0, 0);
  }
}

// 128x128 tile step, 8 waves (k_out): wave-tile 64x32
__device__ __forceinline__ void mm_step8(const u16* As, const u16* Bs, int wr, int wc,
                                         int l, f32x4 acc[4][2]) {
#pragma unroll
  for (int kh = 0; kh < 2; ++kh) {
    bf16x8 a[4], b[2];
#pragma unroll
    for (int m = 0; m < 4; ++m) {
      int row = wr * 64 + m * 16 + (l & 15);
      int ch = (kh * 4 + (l >> 4)) ^ (row & 7);
      a[m] = *(const bf16x8*)(As + row * 64 + ch * 8);
    }
#pragma unroll
    for (int n = 0; n < 2; ++n) {
      int row = wc * 32 + n * 16 + (l & 15);
      int ch = (kh * 4 + (l >> 4)) ^ (row & 7);
      b[n] = *(const bf16x8*)(Bs + row * 64 + ch * 8);
    }
#pragma unroll
    for (int m = 0; m < 4; ++m)
#pragma unroll
      for (int n = 0; n < 2; ++n)
        acc[m][n] = __builtin_amdgcn_mfma_f32_16x16x32_bf16(a[m], b[n], acc[m][n], 0, 0, 0);
  }
}

// 64x64 tile step, 4 waves (poly)
__device__ __forceinline__ void mm64(const u16* As, const u16* Bs, int wr, int wc,
                                     int l, f32x4 acc[2][2]) {
#pragma unroll
  for (int kh = 0; kh < 2; ++kh) {
    bf16x8 a[2], b[2];
#pragma unroll
    for (int m = 0; m < 2; ++m) {
      int row = wr * 32 + m * 16 + (l & 15);
      int ch = (kh * 4 + (l >> 4)) ^ (row & 7);
      a[m] = *(const bf16x8*)(As + row * 64 + ch * 8);
    }
#pragma unroll
    for (int n = 0; n < 2; ++n) {
      int row = wc * 32 + n * 16 + (l & 15);
      int ch = (kh * 4 + (l >> 4)) ^ (row & 7);
      b[n] = *(const bf16x8*)(Bs + row * 64 + ch * 8);
    }
#pragma unroll
    for (int m = 0; m < 2; ++m)
#pragma unroll
      for (int n = 0; n < 2; ++n)
        acc[m][n] = __builtin_amdgcn_mfma_f32_16x16x32_bf16(a[m], b[n], acc[m][n], 0, 0, 0);
  }
}

// ---------------- K0: zero S + colsum + tacc (1,052,672 B = 65792 uint4) --------
__global__ __launch_bounds__(256) void k_zero(uint4* __restrict__ p) {
  p[(size_t)blockIdx.x * 256 + threadIdx.x] = uint4{0u, 0u, 0u, 0u};
}

// ---------------- K1: transpose + colsum + optional xb, coalesced writes -------
// grid (512, 8), 256 thr; tile = 128 batch rows x 64 feats.
// Phase A: fp32 [128][65] LDS tile + colsum partials + xb (bf16 row-major, big ws).
// Phase B: per store instruction, lanes 0..31 write feature f's 128-k run
// (32 x 8B = 256B contiguous), lanes 32..63 write feature f+1.
__global__ __launch_bounds__(256) void k_prep3(const float* __restrict__ x,
                                               u16* __restrict__ xbT,
                                               float* __restrict__ colsum,
                                               u16* __restrict__ xb) {
  __shared__ __attribute__((aligned(16))) float tile[128 * 65];
  __shared__ float red[1024];
  const int t = threadIdx.x;
  const int r0 = blockIdx.x * 128, c0 = blockIdx.y * 64;
  const int c4 = t & 15, rg = t >> 4;
  float cs0 = 0, cs1 = 0, cs2 = 0, cs3 = 0;
#pragma unroll
  for (int p = 0; p < 8; ++p) {
    int r = rg + p * 16;
    float4 v = *(const float4*)(x + (size_t)(r0 + r) * F + c0 + c4 * 4);
    cs0 += v.x; cs1 += v.y; cs2 += v.z; cs3 += v.w;
    float* tp = tile + r * 65 + c4 * 4;
    tp[0] = v.x; tp[1] = v.y; tp[2] = v.z; tp[3] = v.w;
    if (xb) {
      ushort4 o;
      o.x = f2bf(v.x); o.y = f2bf(v.y); o.z = f2bf(v.z); o.w = f2bf(v.w);
      *(ushort4*)(xb + (size_t)(r0 + r) * F + c0 + c4 * 4) = o;
    }
  }
  red[rg * 64 + c4 * 4 + 0] = cs0;
  red[rg * 64 + c4 * 4 + 1] = cs1;
  red[rg * 64 + c4 * 4 + 2] = cs2;
  red[rg * 64 + c4 * 4 + 3] = cs3;
  __syncthreads();
  const int l = t & 63, w = t >> 6;
  const int half = l >> 5, kb = (l & 31) * 4;
#pragma unroll
  for (int it = 0; it < 8; ++it) {
    int f = w * 16 + it * 2 + half;
    ushort4 o;
    o.x = f2bf(tile[(kb + 0) * 65 + f]);
    o.y = f2bf(tile[(kb + 1) * 65 + f]);
    o.z = f2bf(tile[(kb + 2) * 65 + f]);
    o.w = f2bf(tile[(kb + 3) * 65 + f]);
    *(ushort4*)(xbT + (size_t)(c0 + f) * LDT + r0 + kb) = o;
  }
  if (t < 64) {
    float s = 0;
#pragma unroll
    for (int g = 0; g < 16; ++g) s += red[g * 64 + t];
    atomicAdd(colsum + c0 + t, s);
  }
}

// ---------------- K2: S = X^T X, upper-triangle 128-tiles, split-K ----------------
__global__ __launch_bounds__(256) void k_cov(const u16* __restrict__ xbT,
                                             float* __restrict__ S) {
  __shared__ __attribute__((aligned(16))) u16 As[2][128 * 64];
  __shared__ __attribute__((aligned(16))) u16 Bs[2][128 * 64];
  const int b = blockIdx.x;
  const int i = b >> 3;               // 0..39
  const int slab = (b & 7) * 4 + i / 10;
  const int tid = i % 10;
  int ta, tb;
  if (tid < 4)      { ta = 0; tb = tid; }
  else if (tid < 7) { ta = 1; tb = tid - 3; }
  else if (tid < 9) { ta = 2; tb = tid - 5; }
  else              { ta = 3; tb = 3; }
  const int a0 = ta * 128, b0 = tb * 128;
  const size_t kbase = (size_t)slab * 2048;
  const int t = threadIdx.x;
  const int l = t & 63, w = t >> 6, wr = w >> 1, wc = w & 1;
  f32x4 acc[4][4] = {};
  const u16* Abase = xbT + (size_t)a0 * LDT + kbase;
  const u16* Bbase = xbT + (size_t)b0 * LDT + kbase;
  stage_tile(As[0], Abase, LDT, t);
  stage_tile(Bs[0], Bbase, LDT, t);
  __syncthreads();
  for (int it = 0; it < 32; ++it) {
    int cur = it & 1;
    if (it < 31) {
      stage_tile(As[cur ^ 1], Abase + (it + 1) * 64, LDT, t);
      stage_tile(Bs[cur ^ 1], Bbase + (it + 1) * 64, LDT, t);
    }
    mm_step(As[cur], Bs[cur], wr, wc, l, acc);
    __syncthreads();
  }
#pragma unroll
  for (int m = 0; m < 4; ++m) {
    int rg = a0 + wr * 64 + m * 16 + ((l >> 4) << 2);
#pragma unroll
    for (int n = 0; n < 4; ++n) {
      int cg = b0 + wc * 64 + n * 16 + (l & 15);
#pragma unroll
      for (int r = 0; r < 4; ++r)
        atomicAdd(S + (size_t)(rg + r) * F + cg, acc[m][n][r]);
    }
  }
}

// ---------------- K3: finalize mean + E = cov - I ----------------
__global__ __launch_bounds__(256) void k_finalize(const float* __restrict__ S,
                                                  const float* __restrict__ colsum,
                                                  float* __restrict__ mean,
                                                  float* __restrict__ E,
                                                  u16* __restrict__ Eb) {
  int gid = blockIdx.x * 256 + threadIdx.x;
  int i = gid >> 9, j = gid & 511;
  float mi = colsum[i] * (1.0f / 65536.0f);
  float mj = colsum[j] * (1.0f / 65536.0f);
  float sv = ((i >> 7) <= (j >> 7)) ? S[(size_t)i * F + j] : S[(size_t)j * F + i];
  float cov = (sv - 65536.0f * mi * mj) * (1.0f / 65535.0f);
  float e = cov + ((i == j) ? (0.001f - 1.0f) : 0.0f);
  E[gid] = e;
  Eb[gid] = f2bf(e);
  if (gid < F) mean[gid] = colsum[gid] * (1.0f / 65536.0f);
}

// ---------------- K4/K5: degree-4 Taylor of (I+E)^(-1/2) ----------------
__global__ __launch_bounds__(256) void k_poly(char* __restrict__ wsb, int stg) {
  __shared__ __attribute__((aligned(16))) u16 As[2][64 * 64];
  __shared__ __attribute__((aligned(16))) u16 Bs[2][64 * 64];
  const int tile = blockIdx.x;
  const int tr = tile >> 3, tc = tile & 7;
  const int r0 = tr * 64, c0 = tc * 64;
  const u16* Eb  = (const u16*)(wsb + WS_EB);
  const u16* E2b = (const u16*)(wsb + WS_E2B);
  const u16* Gb  = (const u16*)(wsb + WS_GB);
  const u16* Ab; const u16* Bb;
  if (stg == 0) { Ab = Eb;  Bb = Eb; }
  else          { Ab = E2b; Bb = Gb; }
  const int t = threadIdx.x;
  const int l = t & 63, w = t >> 6, wr = w >> 1, wc = w & 1;
  f32x4 acc[2][2] = {};
  stage64(As[0], Ab + (size_t)r0 * F, F, t);
  stage64(Bs[0], Bb + (size_t)c0 * F, F, t);
  __syncthreads();
  for (int it = 0; it < 8; ++it) {
    int cur = it & 1;
    if (it < 7) {
      stage64(As[cur ^ 1], Ab + (size_t)r0 * F + (it + 1) * 64, F, t);
      stage64(Bs[cur ^ 1], Bb + (size_t)c0 * F + (it + 1) * 64, F, t);
    }
    mm64(As[cur], Bs[cur], wr, wc, l, acc);
    __syncthreads();
  }
  const float* Ef  = (const float*)(wsb + WS_E);
  const float* E2f = (const float*)(wsb + WS_E2);
  const float* mean = (const float*)(wsb + WS_MEAN);
  float* tacc = (float*)(wsb + WS_TACC);
  const float c1 = -0.5f, c2 = 0.375f, c3 = -0.3125f, c4 = 35.0f / 128.0f;
#pragma unroll
  for (int n = 0; n < 2; ++n) {
    int cg = c0 + wc * 32 + n * 16 + (l & 15);
    float ts = 0.0f;
#pragma unroll
    for (int m = 0; m < 2; ++m) {
#pragma unroll
      for (int r = 0; r < 4; ++r) {
        int rg = r0 + wr * 32 + m * 16 + ((l >> 4) << 2) + r;
        size_t o = (size_t)rg * F + cg;
        float v = acc[m][n][r];
        if (stg == 0) {
          ((float*)(wsb + WS_E2))[o] = v;
          ((u16*)(wsb + WS_E2B))[o] = f2bf(v);
          ((u16*)(wsb + WS_GB))[o]  = f2bf(c3 * Ef[o] + c4 * v);
        } else {
          float wv = c1 * Ef[o] + c2 * E2f[o] + v + ((rg == cg) ? 1.0f : 0.0f);
          ((u16*)(wsb + WS_WB))[o] = f2bf(wv);
          ts += mean[rg] * wv;
        }
      }
    }
    if (stg == 1) atomicAdd(tacc + cg, ts);
  }
}

// ---------------- K6a: out = (xb@W - tacc)*w + b  (pure bf16 GEMM) --------
__global__ __launch_bounds__(512) void k_out_b(const u16* __restrict__ xb,
                                               const u16* __restrict__ Wb,
                                               const float* __restrict__ tacc,
                                               const float* __restrict__ wgt,
                                               const float* __restrict__ bias,
                                               float* __restrict__ out) {
  __shared__ __attribute__((aligned(16))) u16 As[2][128 * 64];
  __shared__ __attribute__((aligned(16))) u16 Bs[2][128 * 64];
  const int b = blockIdx.x;
  const int i = b >> 3;
  const int rt = (b & 7) * 64 + (i >> 2), ct = i & 3;
  const int i0 = rt * 128, j0 = ct * 128;
  const int t = threadIdx.x;
  const int l = t & 63, w = t >> 6, wr = w >> 2, wc = w & 3;
  f32x4 acc[4][2] = {};
  const u16* Abase = xb + (size_t)i0 * F;
  const u16* Bbase = Wb + (size_t)j0 * F;
  stage512(As[0], Abase, F, t);
  stage512(Bs[0], Bbase, F, t);
  __syncthreads();
  for (int it = 0; it < 8; ++it) {
    int cur = it & 1;
    if (it < 7) {
      stage512(As[cur ^ 1], Abase + (it + 1) * 64, F, t);
      stage512(Bs[cur ^ 1], Bbase + (it + 1) * 64, F, t);
    }
    mm_step8(As[cur], Bs[cur], wr, wc, l, acc);
    __syncthreads();
  }
#pragma unroll
  for (int n = 0; n < 2; ++n) {
    int cg = j0 + wc * 32 + n * 16 + (l & 15);
    float mv = tacc[cg];
    float wv = wgt[cg], bv = bias[cg];
#pragma unroll
    for (int m = 0; m < 4; ++m) {
      int rb = i0 + wr * 64 + m * 16 + ((l >> 4) << 2);
#pragma unroll
      for (int r = 0; r < 4; ++r) {
        size_t o = (size_t)(rb + r) * F + cg;
        __builtin_nontemporal_store((acc[m][n][r] - mv) * wv + bv, out + o);
      }
    }
  }
}

// ---------------- K6b: small-ws fallback (fp32 x reg-staged A) ----------------
__global__ __launch_bounds__(512) void k_out_f(const float* __restrict__ x,
                                               const u16* __restrict__ Wb,
                                               const float* __restrict__ tacc,
                                               const float* __restrict__ wgt,
                                               const float* __restrict__ bias,
                                               float* __restrict__ out) {
  __shared__ __attribute__((aligned(16))) u16 As[2][128 * 64];
  __shared__ __attribute__((aligned(16))) u16 Bs[2][128 * 64];
  const int b = blockIdx.x;
  const int i = b >> 3;
  const int rt = (b & 7) * 64 + (i >> 2), ct = i & 3;
  const int i0 = rt * 128, j0 = ct * 128;
  const int t = threadIdx.x;
  const int l = t & 63, w = t >> 6, wr = w >> 2, wc = w & 3;
  f32x4 acc[4][2] = {};
  float4 ld[4];
  stage512(Bs[0], Wb + (size_t)j0 * F, F, t);
#pragma unroll
  for (int q = 0; q < 4; ++q) {
    int idx = q * 512 + t, r = idx >> 4, kc = idx & 15;
    ld[q] = *(const float4*)(x + (size_t)(i0 + r) * F + kc * 4);
  }
#pragma unroll
  for (int q = 0; q < 4; ++q) {
    int idx = q * 512 + t, r = idx >> 4, kc = idx & 15;
    ushort4 o;
    o.x = f2bf(ld[q].x); o.y = f2bf(ld[q].y); o.z = f2bf(ld[q].z); o.w = f2bf(ld[q].w);
    *(ushort4*)(As[0] + r * 64 + (((kc >> 1) ^ (r & 7)) << 3) + ((kc & 1) << 2)) = o;
  }
  __syncthreads();
  for (int it = 0; it < 8; ++it) {
    int cur = it & 1;
    if (it < 7) {
      int kk = (it + 1) * 64;
#pragma unroll
      for (int q = 0; q < 4; ++q) {
        int idx = q * 512 + t, r = idx >> 4, kc = idx & 15;
        ld[q] = *(const float4*)(x + (size_t)(i0 + r) * F + kk + kc * 4);
      }
      stage512(Bs[cur ^ 1], Wb + (size_t)j0 * F + kk, F, t);
    }
    mm_step8(As[cur], Bs[cur], wr, wc, l, acc);
    if (it < 7) {
#pragma unroll
      for (int q = 0; q < 4; ++q) {
        int idx = q * 512 + t, r = idx >> 4, kc = idx & 15;
        ushort4 o;
        o.x = f2bf(ld[q].x); o.y = f2bf(ld[q].y); o.z = f2bf(ld[q].z); o.w = f2bf(ld[q].w);
        *(ushort4*)(As[cur ^ 1] + r * 64 + (((kc >> 1) ^ (r & 7)) << 3) + ((kc & 1) << 2)) = o;
      }
    }
    __syncthreads();
  }
#pragma unroll
  for (int n = 0; n < 2; ++n) {
    int cg = j0 + wc * 32 + n * 16 + (l & 15);
    float mv = tacc[cg];
    float wv = wgt[cg], bv = bias[cg];
#pragma unroll
    for (int m = 0; m < 4; ++m) {
      int rb = i0 + wr * 64 + m * 16 + ((l >> 4) << 2);
#pragma unroll
      for (int r = 0; r < 4; ++r) {
        size_t o = (size_t)(rb + r) * F + cg;
        __builtin_nontemporal_store((acc[m][n][r] - mv) * wv + bv, out + o);
      }
    }
  }
}

extern "C" void kernel_launch(void* const* d_in, const int* in_sizes, int n_in,
                              void* d_out, int out_size, void* d_ws, size_t ws_size,
                              hipStream_t stream) {
  (void)in_sizes; (void)n_in; (void)out_size;
  const float* x      = (const float*)d_in[0];
  const float* weight = (const float*)d_in[1];
  const float* bias   = (const float*)d_in[2];
  float* out = (float*)d_out;
  char* ws   = (char*)d_ws;
  // xbT (64 MiB) overlays d_out; only read by k_cov, dead before k_out writes.
  u16* xbT = (u16*)d_out;
  const bool big = ws_size >= (size_t)WS_NEED_BIG;
  u16* xb = big ? (u16*)(ws + WS_XB) : nullptr;

  float* S      = (float*)(ws + WS_S);
  float* colsum = (float*)(ws + WS_COLSUM);
  float* tacc   = (float*)(ws + WS_TACC);
  float* mean   = (float*)(ws + WS_MEAN);

  // zero S + colsum + tacc: 1,052,672 B = 65792 uint4 = 257 blocks x 256 thr
  k_zero<<<dim3(257), dim3(256), 0, stream>>>((uint4*)ws);

  k_prep3<<<dim3(512, 8), dim3(256), 0, stream>>>(x, xbT, colsum, xb);
  k_cov<<<dim3(320), dim3(256), 0, stream>>>(xbT, S);
  k_finalize<<<dim3(1024), dim3(256), 0, stream>>>(S, colsum, mean,
                                                   (float*)(ws + WS_E),
                                                   (u16*)(ws + WS_EB));
  k_poly<<<dim3(64), dim3(256), 0, stream>>>(ws, 0);
  k_poly<<<dim3(64), dim3(256), 0, stream>>>(ws, 1);
  if (big) {
    k_out_b<<<dim3(2048), dim3(512), 0, stream>>>(xb, (u16*)(ws + WS_WB),
                                                  tacc, weight, bias, out);
  } else {
    k_out_f<<<dim3(2048), dim3(512), 0, stream>>>(x, (u16*)(ws + WS_WB),
                                                  tacc, weight, bias, out);
  }
}

// Round 11
// 193.989 us; speedup vs baseline: 1.0529x; 1.0529x over previous
//
#include <hip/hip_runtime.h>
#include <hip/hip_bf16.h>

// DecorrelatedBatchNorm1d (ZCA whitening), B=65536, F=512, fp32 in/out.
// Pipeline:
//   K0 k_zero:     zero S + colsum buckets + tacc (custom fill)
//   K1 k_prep3:    xbT = bf16(x)^T (d_out overlay) + xb = bf16(x) row-major (big ws)
//                  + colsum (8 XCD-local buckets). Phase-B LDS reads conflict-free
//                  (k-interleaved, bank=(lk+f)%32), 64B-granule coalesced stores.
//   K2 k_cov:      S = xbT * xbT^T upper-triangle (bf16 MFMA, split-K, atomics)
//   K3 k_finalize: mean (8-bucket sum), E = S/(B-1) corrected - I + eps
//   K4 k_poly s0:  E2 = E@E; G = c3*E + c4*E2        (deg-4 Taylor of (I+E)^-1/2)
//   K5 k_poly s1:  W = I + c1*E + c2*E2 + E2@G -> Wb; tacc = mean^T W
//   K6 k_out_b:    out = (xb@W - tacc)*weight + bias  (pure bf16 MFMA GEMM via
//                   global_load_lds; nontemporal out)   [big ws]
//      k_out_f:    same from fp32 x (reg-staged A)      [small-ws fallback]

#define F 512
#define LDT 65536

typedef unsigned short u16;
using bf16x8 = __attribute__((ext_vector_type(8))) short;
using f32x4  = __attribute__((ext_vector_type(4))) float;

// ---- workspace layout (bytes) ----
#define WS_S      0u
#define WS_COLSUM 1048576u                 /* 8 buckets x 512 floats = 16 KB */
#define WS_TACC   (WS_COLSUM + 16384u)
#define WS_MEAN   (WS_TACC   + 2048u)
#define WS_E      (WS_MEAN   + 2048u)
#define WS_E2     (WS_E   + 1048576u)
#define WS_EB     (WS_E2  + 1048576u)
#define WS_E2B    (WS_EB  + 524288u)
#define WS_GB     (WS_E2B + 524288u)
#define WS_WB     (WS_GB  + 524288u)
#define WS_XB     (WS_WB  + 524288u)
#define WS_NEED_BIG (WS_XB + 67108864u)

__device__ __forceinline__ u16 f2bf(float x) {
  union { float f; unsigned u; } v; v.f = x;
  return (u16)((v.u + 0x7fffu + ((v.u >> 16) & 1u)) >> 16);
}

__device__ __forceinline__ void async_cp16(const void* g, void* l) {
  __builtin_amdgcn_global_load_lds(
      (const __attribute__((address_space(1))) unsigned int*)g,
      (__attribute__((address_space(3))) unsigned int*)l, 16, 0, 0);
}

// ---- [128 rows][64 k] bf16 tile staging ----
// LDS dest linear; source pre-swizzled: LDS row r chunk c holds global chunk c^(r&7).
__device__ __forceinline__ void stage_tile(u16* dst, const u16* src, size_t stride, int t) {
#pragma unroll
  for (int q = 0; q < 4; ++q) {
    int idx = q * 256 + t;
    int c = idx >> 3, ko = idx & 7;
    async_cp16(src + (size_t)c * stride + (size_t)((ko ^ (c & 7)) << 3), dst + idx * 8);
  }
}

__device__ __forceinline__ void stage512(u16* dst, const u16* src, size_t stride, int t) {
#pragma unroll
  for (int q = 0; q < 2; ++q) {
    int idx = q * 512 + t;
    int c = idx >> 3, ko = idx & 7;
    async_cp16(src + (size_t)c * stride + (size_t)((ko ^ (c & 7)) << 3), dst + idx * 8);
  }
}

__device__ __forceinline__ void stage64(u16* dst, const u16* src, size_t stride, int t) {
#pragma unroll
  for (int q = 0; q < 2; ++q) {
    int idx = q * 256 + t;
    int r = idx >> 3, ko = idx & 7;
    async_cp16(src + (size_t)r * stride + (size_t)((ko ^ (r & 7)) << 3), dst + idx * 8);
  }
}

// 128x128 tile step, 4 waves (k_cov)
__device__ __forceinline__ void mm_step(const u16* As, const u16* Bs, int wr, int wc,
                                        int l, f32x4 acc[4][4]) {
#pragma unroll
  for (int kh = 0; kh < 2; ++kh) {
    bf16x8 a[4], b[4];
#pragma unroll
    for (int m = 0; m < 4; ++m) {
      int row = wr * 64 + m * 16 + (l & 15);
      int ch = (kh * 4 + (l >> 4)) ^ (row & 7);
      a[m] = *(const bf16x8*)(As + row * 64 + ch * 8);
    }
#pragma unroll
    for (int n = 0; n < 4; ++n) {
      int row = wc * 64 + n * 16 + (l & 15);
      int ch = (kh * 4 + (l >> 4)) ^ (row & 7);
      b[n] = *(const bf16x8*)(Bs + row * 64 + ch * 8);
    }
#pragma unroll
    for (int m = 0; m < 4; ++m)
#pragma unroll
      for (int n = 0; n < 4; ++n)
        acc[m][n] = __builtin_amdgcn_mfma_f32_16x16x32_bf16(a[m], b[n], acc[m][n], 0, 0, 0);
  }
}

// 128x128 tile step, 8 waves (k_out): wave-tile 64x32
__device__ __forceinline__ void mm_step8(const u16* As, const u16* Bs, int wr, int wc,
                                         int l, f32x4 acc[4][2]) {
#pragma unroll
  for (int kh = 0; kh < 2; ++kh) {
    bf16x8 a[4], b[2];
#pragma unroll
    for (int m = 0; m < 4; ++m) {
      int row = wr * 64 + m * 16 + (l & 15);
      int ch = (kh * 4 + (l >> 4)) ^ (row & 7);
      a[m] = *(const bf16x8*)(As + row * 64 + ch * 8);
    }
#pragma unroll
    for (int n = 0; n < 2; ++n) {
      int row = wc * 32 + n * 16 + (l & 15);
      int ch = (kh * 4 + (l >> 4)) ^ (row & 7);
      b[n] = *(const bf16x8*)(Bs + row * 64 + ch * 8);
    }
#pragma unroll
    for (int m = 0; m < 4; ++m)
#pragma unroll
      for (int n = 0; n < 2; ++n)
        acc[m][n] = __builtin_amdgcn_mfma_f32_16x16x32_bf16(a[m], b[n], acc[m][n], 0, 0, 0);
  }
}

// 64x64 tile step, 4 waves (poly)
__device__ __forceinline__ void mm64(const u16* As, const u16* Bs, int wr, int wc,
                                     int l, f32x4 acc[2][2]) {
#pragma unroll
  for (int kh = 0; kh < 2; ++kh) {
    bf16x8 a[2], b[2];
#pragma unroll
    for (int m = 0; m < 2; ++m) {
      int row = wr * 32 + m * 16 + (l & 15);
      int ch = (kh * 4 + (l >> 4)) ^ (row & 7);
      a[m] = *(const bf16x8*)(As + row * 64 + ch * 8);
    }
#pragma unroll
    for (int n = 0; n < 2; ++n) {
      int row = wc * 32 + n * 16 + (l & 15);
      int ch = (kh * 4 + (l >> 4)) ^ (row & 7);
      b[n] = *(const bf16x8*)(Bs + row * 64 + ch * 8);
    }
#pragma unroll
    for (int m = 0; m < 2; ++m)
#pragma unroll
      for (int n = 0; n < 2; ++n)
        acc[m][n] = __builtin_amdgcn_mfma_f32_16x16x32_bf16(a[m], b[n], acc[m][n], 0, 0, 0);
  }
}

// ---------------- K0: zero S + colsum buckets + tacc ----------------
// 1,067,008 B -> 261 blocks x 256 thr x 16 B (overrun into MEAN is harmless:
// finalize rewrites mean before any read).
__global__ __launch_bounds__(256) void k_zero(uint4* __restrict__ p) {
  p[(size_t)blockIdx.x * 256 + threadIdx.x] = uint4{0u, 0u, 0u, 0u};
}

// ---------------- K1: transpose + bucketed colsum + optional xb ----------------
// grid (512, 8), 256 thr; tile = 128 batch rows x 64 feats.
// Phase A: fp32 [128][65] LDS tile + colsum partials + xb (bf16 row-major, big ws).
// Phase B (conflict-free): lane l (fsel=l>>5, lk=l&31) reads k in {lk,lk+32,lk+64,
// lk+96} for feature f -> bank=(lk+f)%32, all distinct; stores 4x u16, each
// half-wave = 64B contiguous run of a feature row.
// colsum: 8 buckets indexed rt&7 (== XCD id for this grid) -> XCD-local atomics.
__global__ __launch_bounds__(256, 4) void k_prep3(const float* __restrict__ x,
                                                  u16* __restrict__ xbT,
                                                  float* __restrict__ colsum,
                                                  u16* __restrict__ xb) {
  __shared__ __attribute__((aligned(16))) float tile[128 * 65];
  __shared__ float red[1024];
  const int t = threadIdx.x;
  const int r0 = blockIdx.x * 128, c0 = blockIdx.y * 64;
  const int c4 = t & 15, rg = t >> 4;
  float cs0 = 0, cs1 = 0, cs2 = 0, cs3 = 0;
#pragma unroll
  for (int p = 0; p < 8; ++p) {
    int r = rg + p * 16;
    float4 v = *(const float4*)(x + (size_t)(r0 + r) * F + c0 + c4 * 4);
    cs0 += v.x; cs1 += v.y; cs2 += v.z; cs3 += v.w;
    float* tp = tile + r * 65 + c4 * 4;
    tp[0] = v.x; tp[1] = v.y; tp[2] = v.z; tp[3] = v.w;
    if (xb) {
      ushort4 o;
      o.x = f2bf(v.x); o.y = f2bf(v.y); o.z = f2bf(v.z); o.w = f2bf(v.w);
      *(ushort4*)(xb + (size_t)(r0 + r) * F + c0 + c4 * 4) = o;
    }
  }
  red[rg * 64 + c4 * 4 + 0] = cs0;
  red[rg * 64 + c4 * 4 + 1] = cs1;
  red[rg * 64 + c4 * 4 + 2] = cs2;
  red[rg * 64 + c4 * 4 + 3] = cs3;
  __syncthreads();
  const int l = t & 63, w = t >> 6;
  const int fsel = l >> 5, lk = l & 31;
#pragma unroll
  for (int fo = 0; fo < 8; ++fo) {
    int f = w * 16 + fo * 2 + fsel;
    u16* dst = xbT + (size_t)(c0 + f) * LDT + r0 + lk;
#pragma unroll
    for (int s = 0; s < 4; ++s)
      dst[s * 32] = f2bf(tile[(lk + s * 32) * 65 + f]);
  }
  if (t < 64) {
    float s = 0;
#pragma unroll
    for (int g = 0; g < 16; ++g) s += red[g * 64 + t];
    atomicAdd(colsum + (blockIdx.x & 7) * 512 + c0 + t, s);
  }
}

// ---------------- K2: S = X^T X, upper-triangle 128-tiles, split-K ----------------
__global__ __launch_bounds__(256) void k_cov(const u16* __restrict__ xbT,
                                             float* __restrict__ S) {
  __shared__ __attribute__((aligned(16))) u16 As[2][128 * 64];
  __shared__ __attribute__((aligned(16))) u16 Bs[2][128 * 64];
  const int b = blockIdx.x;
  const int i = b >> 3;               // 0..39
  const int slab = (b & 7) * 4 + i / 10;
  const int tid = i % 10;
  int ta, tb;
  if (tid < 4)      { ta = 0; tb = tid; }
  else if (tid < 7) { ta = 1; tb = tid - 3; }
  else if (tid < 9) { ta = 2; tb = tid - 5; }
  else              { ta = 3; tb = 3; }
  const int a0 = ta * 128, b0 = tb * 128;
  const size_t kbase = (size_t)slab * 2048;
  const int t = threadIdx.x;
  const int l = t & 63, w = t >> 6, wr = w >> 1, wc = w & 1;
  f32x4 acc[4][4] = {};
  const u16* Abase = xbT + (size_t)a0 * LDT + kbase;
  const u16* Bbase = xbT + (size_t)b0 * LDT + kbase;
  stage_tile(As[0], Abase, LDT, t);
  stage_tile(Bs[0], Bbase, LDT, t);
  __syncthreads();
  for (int it = 0; it < 32; ++it) {
    int cur = it & 1;
    if (it < 31) {
      stage_tile(As[cur ^ 1], Abase + (it + 1) * 64, LDT, t);
      stage_tile(Bs[cur ^ 1], Bbase + (it + 1) * 64, LDT, t);
    }
    mm_step(As[cur], Bs[cur], wr, wc, l, acc);
    __syncthreads();
  }
#pragma unroll
  for (int m = 0; m < 4; ++m) {
    int rg = a0 + wr * 64 + m * 16 + ((l >> 4) << 2);
#pragma unroll
    for (int n = 0; n < 4; ++n) {
      int cg = b0 + wc * 64 + n * 16 + (l & 15);
#pragma unroll
      for (int r = 0; r < 4; ++r)
        atomicAdd(S + (size_t)(rg + r) * F + cg, acc[m][n][r]);
    }
  }
}

// ---------------- K3: finalize mean + E = cov - I ----------------
__global__ __launch_bounds__(256) void k_finalize(const float* __restrict__ S,
                                                  const float* __restrict__ colsum,
                                                  float* __restrict__ mean,
                                                  float* __restrict__ E,
                                                  u16* __restrict__ Eb) {
  int gid = blockIdx.x * 256 + threadIdx.x;
  int i = gid >> 9, j = gid & 511;
  float si = 0.0f, sj = 0.0f;
#pragma unroll
  for (int bkt = 0; bkt < 8; ++bkt) {
    si += colsum[bkt * 512 + i];
    sj += colsum[bkt * 512 + j];
  }
  float mi = si * (1.0f / 65536.0f);
  float mj = sj * (1.0f / 65536.0f);
  float sv = ((i >> 7) <= (j >> 7)) ? S[(size_t)i * F + j] : S[(size_t)j * F + i];
  float cov = (sv - 65536.0f * mi * mj) * (1.0f / 65535.0f);
  float e = cov + ((i == j) ? (0.001f - 1.0f) : 0.0f);
  E[gid] = e;
  Eb[gid] = f2bf(e);
  if (gid < F) mean[gid] = mi;  // i == gid>>9 == 0 only for gid<512 -> use recompute
  if (gid < F) {
    float s = 0.0f;
#pragma unroll
    for (int bkt = 0; bkt < 8; ++bkt) s += colsum[bkt * 512 + gid];
    mean[gid] = s * (1.0f / 65536.0f);
  }
}

// ---------------- K4/K5: degree-4 Taylor of (I+E)^(-1/2) ----------------
__global__ __launch_bounds__(256) void k_poly(char* __restrict__ wsb, int stg) {
  __shared__ __attribute__((aligned(16))) u16 As[2][64 * 64];
  __shared__ __attribute__((aligned(16))) u16 Bs[2][64 * 64];
  const int tile = blockIdx.x;
  const int tr = tile >> 3, tc = tile & 7;
  const int r0 = tr * 64, c0 = tc * 64;
  const u16* Eb  = (const u16*)(wsb + WS_EB);
  const u16* E2b = (const u16*)(wsb + WS_E2B);
  const u16* Gb  = (const u16*)(wsb + WS_GB);
  const u16* Ab; const u16* Bb;
  if (stg == 0) { Ab = Eb;  Bb = Eb; }
  else          { Ab = E2b; Bb = Gb; }
  const int t = threadIdx.x;
  const int l = t & 63, w = t >> 6, wr = w >> 1, wc = w & 1;
  f32x4 acc[2][2] = {};
  stage64(As[0], Ab + (size_t)r0 * F, F, t);
  stage64(Bs[0], Bb + (size_t)c0 * F, F, t);
  __syncthreads();
  for (int it = 0; it < 8; ++it) {
    int cur = it & 1;
    if (it < 7) {
      stage64(As[cur ^ 1], Ab + (size_t)r0 * F + (it + 1) * 64, F, t);
      stage64(Bs[cur ^ 1], Bb + (size_t)c0 * F + (it + 1) * 64, F, t);
    }
    mm64(As[cur], Bs[cur], wr, wc, l, acc);
    __syncthreads();
  }
  const float* Ef  = (const float*)(wsb + WS_E);
  const float* E2f = (const float*)(wsb + WS_E2);
  const float* mean = (const float*)(wsb + WS_MEAN);
  float* tacc = (float*)(wsb + WS_TACC);
  const float c1 = -0.5f, c2 = 0.375f, c3 = -0.3125f, c4 = 35.0f / 128.0f;
#pragma unroll
  for (int n = 0; n < 2; ++n) {
    int cg = c0 + wc * 32 + n * 16 + (l & 15);
    float ts = 0.0f;
#pragma unroll
    for (int m = 0; m < 2; ++m) {
#pragma unroll
      for (int r = 0; r < 4; ++r) {
        int rg = r0 + wr * 32 + m * 16 + ((l >> 4) << 2) + r;
        size_t o = (size_t)rg * F + cg;
        float v = acc[m][n][r];
        if (stg == 0) {
          ((float*)(wsb + WS_E2))[o] = v;
          ((u16*)(wsb + WS_E2B))[o] = f2bf(v);
          ((u16*)(wsb + WS_GB))[o]  = f2bf(c3 * Ef[o] + c4 * v);
        } else {
          float wv = c1 * Ef[o] + c2 * E2f[o] + v + ((rg == cg) ? 1.0f : 0.0f);
          ((u16*)(wsb + WS_WB))[o] = f2bf(wv);
          ts += mean[rg] * wv;
        }
      }
    }
    if (stg == 1) atomicAdd(tacc + cg, ts);
  }
}

// ---------------- K6a: out = (xb@W - tacc)*w + b  (pure bf16 GEMM) --------
__global__ __launch_bounds__(512) void k_out_b(const u16* __restrict__ xb,
                                               const u16* __restrict__ Wb,
                                               const float* __restrict__ tacc,
                                               const float* __restrict__ wgt,
                                               const float* __restrict__ bias,
                                               float* __restrict__ out) {
  __shared__ __attribute__((aligned(16))) u16 As[2][128 * 64];
  __shared__ __attribute__((aligned(16))) u16 Bs[2][128 * 64];
  const int b = blockIdx.x;
  const int i = b >> 3;
  const int rt = (b & 7) * 64 + (i >> 2), ct = i & 3;
  const int i0 = rt * 128, j0 = ct * 128;
  const int t = threadIdx.x;
  const int l = t & 63, w = t >> 6, wr = w >> 2, wc = w & 3;
  f32x4 acc[4][2] = {};
  const u16* Abase = xb + (size_t)i0 * F;
  const u16* Bbase = Wb + (size_t)j0 * F;
  stage512(As[0], Abase, F, t);
  stage512(Bs[0], Bbase, F, t);
  __syncthreads();
  for (int it = 0; it < 8; ++it) {
    int cur = it & 1;
    if (it < 7) {
      stage512(As[cur ^ 1], Abase + (it + 1) * 64, F, t);
      stage512(Bs[cur ^ 1], Bbase + (it + 1) * 64, F, t);
    }
    mm_step8(As[cur], Bs[cur], wr, wc, l, acc);
    __syncthreads();
  }
#pragma unroll
  for (int n = 0; n < 2; ++n) {
    int cg = j0 + wc * 32 + n * 16 + (l & 15);
    float mv = tacc[cg];
    float wv = wgt[cg], bv = bias[cg];
#pragma unroll
    for (int m = 0; m < 4; ++m) {
      int rb = i0 + wr * 64 + m * 16 + ((l >> 4) << 2);
#pragma unroll
      for (int r = 0; r < 4; ++r) {
        size_t o = (size_t)(rb + r) * F + cg;
        __builtin_nontemporal_store((acc[m][n][r] - mv) * wv + bv, out + o);
      }
    }
  }
}

// ---------------- K6b: small-ws fallback (fp32 x reg-staged A) ----------------
__global__ __launch_bounds__(512) void k_out_f(const float* __restrict__ x,
                                               const u16* __restrict__ Wb,
                                               const float* __restrict__ tacc,
                                               const float* __restrict__ wgt,
                                               const float* __restrict__ bias,
                                               float* __restrict__ out) {
  __shared__ __attribute__((aligned(16))) u16 As[2][128 * 64];
  __shared__ __attribute__((aligned(16))) u16 Bs[2][128 * 64];
  const int b = blockIdx.x;
  const int i = b >> 3;
  const int rt = (b & 7) * 64 + (i >> 2), ct = i & 3;
  const int i0 = rt * 128, j0 = ct * 128;
  const int t = threadIdx.x;
  const int l = t & 63, w = t >> 6, wr = w >> 2, wc = w & 3;
  f32x4 acc[4][2] = {};
  float4 ld[4];
  stage512(Bs[0], Wb + (size_t)j0 * F, F, t);
#pragma unroll
  for (int q = 0; q < 4; ++q) {
    int idx = q * 512 + t, r = idx >> 4, kc = idx & 15;
    ld[q] = *(const float4*)(x + (size_t)(i0 + r) * F + kc * 4);
  }
#pragma unroll
  for (int q = 0; q < 4; ++q) {
    int idx = q * 512 + t, r = idx >> 4, kc = idx & 15;
    ushort4 o;
    o.x = f2bf(ld[q].x); o.y = f2bf(ld[q].y); o.z = f2bf(ld[q].z); o.w = f2bf(ld[q].w);
    *(ushort4*)(As[0] + r * 64 + (((kc >> 1) ^ (r & 7)) << 3) + ((kc & 1) << 2)) = o;
  }
  __syncthreads();
  for (int it = 0; it < 8; ++it) {
    int cur = it & 1;
    if (it < 7) {
      int kk = (it + 1) * 64;
#pragma unroll
      for (int q = 0; q < 4; ++q) {
        int idx = q * 512 + t, r = idx >> 4, kc = idx & 15;
        ld[q] = *(const float4*)(x + (size_t)(i0 + r) * F + kk + kc * 4);
      }
      stage512(Bs[cur ^ 1], Wb + (size_t)j0 * F + kk, F, t);
    }
    mm_step8(As[cur], Bs[cur], wr, wc, l, acc);
    if (it < 7) {
#pragma unroll
      for (int q = 0; q < 4; ++q) {
        int idx = q * 512 + t, r = idx >> 4, kc = idx & 15;
        ushort4 o;
        o.x = f2bf(ld[q].x); o.y = f2bf(ld[q].y); o.z = f2bf(ld[q].z); o.w = f2bf(ld[q].w);
        *(ushort4*)(As[cur ^ 1] + r * 64 + (((kc >> 1) ^ (r & 7)) << 3) + ((kc & 1) << 2)) = o;
      }
    }
    __syncthreads();
  }
#pragma unroll
  for (int n = 0; n < 2; ++n) {
    int cg = j0 + wc * 32 + n * 16 + (l & 15);
    float mv = tacc[cg];
    float wv = wgt[cg], bv = bias[cg];
#pragma unroll
    for (int m = 0; m < 4; ++m) {
      int rb = i0 + wr * 64 + m * 16 + ((l >> 4) << 2);
#pragma unroll
      for (int r = 0; r < 4; ++r) {
        size_t o = (size_t)(rb + r) * F + cg;
        __builtin_nontemporal_store((acc[m][n][r] - mv) * wv + bv, out + o);
      }
    }
  }
}

extern "C" void kernel_launch(void* const* d_in, const int* in_sizes, int n_in,
                              void* d_out, int out_size, void* d_ws, size_t ws_size,
                              hipStream_t stream) {
  (void)in_sizes; (void)n_in; (void)out_size;
  const float* x      = (const float*)d_in[0];
  const float* weight = (const float*)d_in[1];
  const float* bias   = (const float*)d_in[2];
  float* out = (float*)d_out;
  char* ws   = (char*)d_ws;
  // xbT (64 MiB) overlays d_out; only read by k_cov, dead before k_out writes.
  u16* xbT = (u16*)d_out;
  const bool big = ws_size >= (size_t)WS_NEED_BIG;
  u16* xb = big ? (u16*)(ws + WS_XB) : nullptr;

  float* S      = (float*)(ws + WS_S);
  float* colsum = (float*)(ws + WS_COLSUM);
  float* tacc   = (float*)(ws + WS_TACC);
  float* mean   = (float*)(ws + WS_MEAN);

  // zero S + colsum buckets + tacc (261 * 4096 B covers 1,067,008 B + slack
  // into mean, which finalize rewrites before reading)
  k_zero<<<dim3(261), dim3(256), 0, stream>>>((uint4*)ws);

  k_prep3<<<dim3(512, 8), dim3(256), 0, stream>>>(x, xbT, colsum, xb);
  k_cov<<<dim3(320), dim3(256), 0, stream>>>(xbT, S);
  k_finalize<<<dim3(1024), dim3(256), 0, stream>>>(S, colsum, mean,
                                                   (float*)(ws + WS_E),
                                                   (u16*)(ws + WS_EB));
  k_poly<<<dim3(64), dim3(256), 0, stream>>>(ws, 0);
  k_poly<<<dim3(64), dim3(256), 0, stream>>>(ws, 1);
  if (big) {
    k_out_b<<<dim3(2048), dim3(512), 0, stream>>>(xb, (u16*)(ws + WS_WB),
                                                  tacc, weight, bias, out);
  } else {
    k_out_f<<<dim3(2048), dim3(512), 0, stream>>>(x, (u16*)(ws + WS_WB),
                                                  tacc, weight, bias, out);
  }
}

// Round 12
// 190.368 us; speedup vs baseline: 1.0730x; 1.0190x over previous
//
#include <hip/hip_runtime.h>
#include <hip/hip_bf16.h>

// DecorrelatedBatchNorm1d (ZCA whitening), B=65536, F=512, fp32 in/out.
// Pipeline:
//   K0 k_zero:     zero S + colsum buckets + tacc (custom fill)
//   K1 k_prep4:    xbT = bf16(x)^T (d_out overlay) + xb = bf16(x) row-major (big ws)
//                  + colsum (8 XCD-local buckets). bf16 swizzled LDS tile (20.5KB,
//                  ~7 blocks/CU); phase-B conflict-free b32 reads + 8B/lane stores
//                  (256B contiguous per feature).
//   K2 k_cov:      S = xbT * xbT^T upper-triangle (bf16 MFMA, split-K, atomics)
//   K3 k_finalize: mean (8-bucket sum), E = S/(B-1) corrected - I + eps
//   K4 k_poly s0:  E2 = E@E; G = c3*E + c4*E2        (deg-4 Taylor of (I+E)^-1/2)
//   K5 k_poly s1:  W = I + c1*E + c2*E2 + E2@G -> Wb; tacc = mean^T W
//   K6 k_out_b:    out = (xb@W - tacc)*weight + bias  (pure bf16 MFMA GEMM via
//                   global_load_lds; nontemporal out)   [big ws]
//      k_out_f:    same from fp32 x (reg-staged A)      [small-ws fallback]

#define F 512
#define LDT 65536

typedef unsigned short u16;
using bf16x8 = __attribute__((ext_vector_type(8))) short;
using f32x4  = __attribute__((ext_vector_type(4))) float;

// ---- workspace layout (bytes) ----
#define WS_S      0u
#define WS_COLSUM 1048576u                 /* 8 buckets x 512 floats = 16 KB */
#define WS_TACC   (WS_COLSUM + 16384u)
#define WS_MEAN   (WS_TACC   + 2048u)
#define WS_E      (WS_MEAN   + 2048u)
#define WS_E2     (WS_E   + 1048576u)
#define WS_EB     (WS_E2  + 1048576u)
#define WS_E2B    (WS_EB  + 524288u)
#define WS_GB     (WS_E2B + 524288u)
#define WS_WB     (WS_GB  + 524288u)
#define WS_XB     (WS_WB  + 524288u)
#define WS_NEED_BIG (WS_XB + 67108864u)

__device__ __forceinline__ u16 f2bf(float x) {
  union { float f; unsigned u; } v; v.f = x;
  return (u16)((v.u + 0x7fffu + ((v.u >> 16) & 1u)) >> 16);
}

// zip of two dwords at u16 granularity (verified on-device, round-5 k_tr):
// zlo = [A.lo16 | B.lo16<<16], zhi = [A.hi16 | B.hi16<<16]
__device__ __forceinline__ unsigned zlo(unsigned A, unsigned B) {
  return __builtin_amdgcn_perm(B, A, 0x05040100u);
}
__device__ __forceinline__ unsigned zhi(unsigned A, unsigned B) {
  return __builtin_amdgcn_perm(B, A, 0x07060302u);
}

__device__ __forceinline__ void async_cp16(const void* g, void* l) {
  __builtin_amdgcn_global_load_lds(
      (const __attribute__((address_space(1))) unsigned int*)g,
      (__attribute__((address_space(3))) unsigned int*)l, 16, 0, 0);
}

// ---- [128 rows][64 k] bf16 tile staging ----
// LDS dest linear; source pre-swizzled: LDS row r chunk c holds global chunk c^(r&7).
__device__ __forceinline__ void stage_tile(u16* dst, const u16* src, size_t stride, int t) {
#pragma unroll
  for (int q = 0; q < 4; ++q) {
    int idx = q * 256 + t;
    int c = idx >> 3, ko = idx & 7;
    async_cp16(src + (size_t)c * stride + (size_t)((ko ^ (c & 7)) << 3), dst + idx * 8);
  }
}

__device__ __forceinline__ void stage512(u16* dst, const u16* src, size_t stride, int t) {
#pragma unroll
  for (int q = 0; q < 2; ++q) {
    int idx = q * 512 + t;
    int c = idx >> 3, ko = idx & 7;
    async_cp16(src + (size_t)c * stride + (size_t)((ko ^ (c & 7)) << 3), dst + idx * 8);
  }
}

__device__ __forceinline__ void stage64(u16* dst, const u16* src, size_t stride, int t) {
#pragma unroll
  for (int q = 0; q < 2; ++q) {
    int idx = q * 256 + t;
    int r = idx >> 3, ko = idx & 7;
    async_cp16(src + (size_t)r * stride + (size_t)((ko ^ (r & 7)) << 3), dst + idx * 8);
  }
}

// 128x128 tile step, 4 waves (k_cov)
__device__ __forceinline__ void mm_step(const u16* As, const u16* Bs, int wr, int wc,
                                        int l, f32x4 acc[4][4]) {
#pragma unroll
  for (int kh = 0; kh < 2; ++kh) {
    bf16x8 a[4], b[4];
#pragma unroll
    for (int m = 0; m < 4; ++m) {
      int row = wr * 64 + m * 16 + (l & 15);
      int ch = (kh * 4 + (l >> 4)) ^ (row & 7);
      a[m] = *(const bf16x8*)(As + row * 64 + ch * 8);
    }
#pragma unroll
    for (int n = 0; n < 4; ++n) {
      int row = wc * 64 + n * 16 + (l & 15);
      int ch = (kh * 4 + (l >> 4)) ^ (row & 7);
      b[n] = *(const bf16x8*)(Bs + row * 64 + ch * 8);
    }
#pragma unroll
    for (int m = 0; m < 4; ++m)
#pragma unroll
      for (int n = 0; n < 4; ++n)
        acc[m][n] = __builtin_amdgcn_mfma_f32_16x16x32_bf16(a[m], b[n], acc[m][n], 0, 0, 0);
  }
}

// 128x128 tile step, 8 waves (k_out): wave-tile 64x32
__device__ __forceinline__ void mm_step8(const u16* As, const u16* Bs, int wr, int wc,
                                         int l, f32x4 acc[4][2]) {
#pragma unroll
  for (int kh = 0; kh < 2; ++kh) {
    bf16x8 a[4], b[2];
#pragma unroll
    for (int m = 0; m < 4; ++m) {
      int row = wr * 64 + m * 16 + (l & 15);
      int ch = (kh * 4 + (l >> 4)) ^ (row & 7);
      a[m] = *(const bf16x8*)(As + row * 64 + ch * 8);
    }
#pragma unroll
    for (int n = 0; n < 2; ++n) {
      int row = wc * 32 + n * 16 + (l & 15);
      int ch = (kh * 4 + (l >> 4)) ^ (row & 7);
      b[n] = *(const bf16x8*)(Bs + row * 64 + ch * 8);
    }
#pragma unroll
    for (int m = 0; m < 4; ++m)
#pragma unroll
      for (int n = 0; n < 2; ++n)
        acc[m][n] = __builtin_amdgcn_mfma_f32_16x16x32_bf16(a[m], b[n], acc[m][n], 0, 0, 0);
  }
}

// 64x64 tile step, 4 waves (poly)
__device__ __forceinline__ void mm64(const u16* As, const u16* Bs, int wr, int wc,
                                     int l, f32x4 acc[2][2]) {
#pragma unroll
  for (int kh = 0; kh < 2; ++kh) {
    bf16x8 a[2], b[2];
#pragma unroll
    for (int m = 0; m < 2; ++m) {
      int row = wr * 32 + m * 16 + (l & 15);
      int ch = (kh * 4 + (l >> 4)) ^ (row & 7);
      a[m] = *(const bf16x8*)(As + row * 64 + ch * 8);
    }
#pragma unroll
    for (int n = 0; n < 2; ++n) {
      int row = wc * 32 + n * 16 + (l & 15);
      int ch = (kh * 4 + (l >> 4)) ^ (row & 7);
      b[n] = *(const bf16x8*)(Bs + row * 64 + ch * 8);
    }
#pragma unroll
    for (int m = 0; m < 2; ++m)
#pragma unroll
      for (int n = 0; n < 2; ++n)
        acc[m][n] = __builtin_amdgcn_mfma_f32_16x16x32_bf16(a[m], b[n], acc[m][n], 0, 0, 0);
  }
}

// ---------------- K0: zero S + colsum buckets + tacc ----------------
// 1,067,008 B -> 261 blocks x 256 thr x 16 B (overrun into MEAN is harmless:
// finalize rewrites mean before any read).
__global__ __launch_bounds__(256) void k_zero(uint4* __restrict__ p) {
  p[(size_t)blockIdx.x * 256 + threadIdx.x] = uint4{0u, 0u, 0u, 0u};
}

// ---------------- K1: transpose + bucketed colsum + optional xb ----------------
// grid (512, 8), 256 thr; tile = 128 batch rows x 64 feats.
// Phase A: fp32 loads -> convert once -> xb store + bf16 swizzled LDS tile
//   (elem (r,f) at u16 addr r*64 + (f ^ (((r>>2)&15)<<2))). 20.5KB LDS.
// Phase B: lane lk=l&31 owns k-run 4lk..4lk+3; reads 4x ds_read_b32 (feature
//   pair), banks (fp>>1)^((lk&15)<<1) -> 2-way free; zip via v_perm; stores
//   uint2 (8B/lane) -> 256B contiguous per feature.
// colsum: 8 buckets indexed blockIdx.x&7 (== XCD) -> XCD-local atomics.
__global__ __launch_bounds__(256, 6) void k_prep4(const float* __restrict__ x,
                                                  u16* __restrict__ xbT,
                                                  float* __restrict__ colsum,
                                                  u16* __restrict__ xb) {
  __shared__ __attribute__((aligned(16))) u16 tile[128 * 64];
  __shared__ float red[1024];
  const int t = threadIdx.x;
  const int r0 = blockIdx.x * 128, c0 = blockIdx.y * 64;
  const int c4 = t & 15, rg = t >> 4;
  float cs0 = 0, cs1 = 0, cs2 = 0, cs3 = 0;
#pragma unroll
  for (int p = 0; p < 8; ++p) {
    int r = rg + p * 16;
    float4 v = *(const float4*)(x + (size_t)(r0 + r) * F + c0 + c4 * 4);
    cs0 += v.x; cs1 += v.y; cs2 += v.z; cs3 += v.w;
    ushort4 o;
    o.x = f2bf(v.x); o.y = f2bf(v.y); o.z = f2bf(v.z); o.w = f2bf(v.w);
    if (xb) *(ushort4*)(xb + (size_t)(r0 + r) * F + c0 + c4 * 4) = o;
    int fx = (c4 * 4) ^ (((r >> 2) & 15) << 2);
    *(ushort4*)(tile + r * 64 + fx) = o;
  }
  red[rg * 64 + c4 * 4 + 0] = cs0;
  red[rg * 64 + c4 * 4 + 1] = cs1;
  red[rg * 64 + c4 * 4 + 2] = cs2;
  red[rg * 64 + c4 * 4 + 3] = cs3;
  __syncthreads();
  const int l = t & 63, w = t >> 6;
  const int lk = l & 31, ph = l >> 5;
  const int swz = (lk & 15) << 2;
#pragma unroll
  for (int fo = 0; fo < 4; ++fo) {
    int fp = w * 16 + fo * 4 + ph * 2;          // even feature-pair base
    int fx = fp ^ swz;
    unsigned d0 = *(const unsigned*)(tile + (4 * lk + 0) * 64 + fx);
    unsigned d1 = *(const unsigned*)(tile + (4 * lk + 1) * 64 + fx);
    unsigned d2 = *(const unsigned*)(tile + (4 * lk + 2) * 64 + fx);
    unsigned d3 = *(const unsigned*)(tile + (4 * lk + 3) * 64 + fx);
    uint2 lo, hi;
    lo.x = zlo(d0, d1); lo.y = zlo(d2, d3);
    hi.x = zhi(d0, d1); hi.y = zhi(d2, d3);
    *(uint2*)(xbT + (size_t)(c0 + fp)     * LDT + r0 + 4 * lk) = lo;
    *(uint2*)(xbT + (size_t)(c0 + fp + 1) * LDT + r0 + 4 * lk) = hi;
  }
  if (t < 64) {
    float s = 0;
#pragma unroll
    for (int g = 0; g < 16; ++g) s += red[g * 64 + t];
    atomicAdd(colsum + (blockIdx.x & 7) * 512 + c0 + t, s);
  }
}

// ---------------- K2: S = X^T X, upper-triangle 128-tiles, split-K ----------------
__global__ __launch_bounds__(256) void k_cov(const u16* __restrict__ xbT,
                                             float* __restrict__ S) {
  __shared__ __attribute__((aligned(16))) u16 As[2][128 * 64];
  __shared__ __attribute__((aligned(16))) u16 Bs[2][128 * 64];
  const int b = blockIdx.x;
  const int i = b >> 3;               // 0..39
  const int slab = (b & 7) * 4 + i / 10;
  const int tid = i % 10;
  int ta, tb;
  if (tid < 4)      { ta = 0; tb = tid; }
  else if (tid < 7) { ta = 1; tb = tid - 3; }
  else if (tid < 9) { ta = 2; tb = tid - 5; }
  else              { ta = 3; tb = 3; }
  const int a0 = ta * 128, b0 = tb * 128;
  const size_t kbase = (size_t)slab * 2048;
  const int t = threadIdx.x;
  const int l = t & 63, w = t >> 6, wr = w >> 1, wc = w & 1;
  f32x4 acc[4][4] = {};
  const u16* Abase = xbT + (size_t)a0 * LDT + kbase;
  const u16* Bbase = xbT + (size_t)b0 * LDT + kbase;
  stage_tile(As[0], Abase, LDT, t);
  stage_tile(Bs[0], Bbase, LDT, t);
  __syncthreads();
  for (int it = 0; it < 32; ++it) {
    int cur = it & 1;
    if (it < 31) {
      stage_tile(As[cur ^ 1], Abase + (it + 1) * 64, LDT, t);
      stage_tile(Bs[cur ^ 1], Bbase + (it + 1) * 64, LDT, t);
    }
    mm_step(As[cur], Bs[cur], wr, wc, l, acc);
    __syncthreads();
  }
#pragma unroll
  for (int m = 0; m < 4; ++m) {
    int rg = a0 + wr * 64 + m * 16 + ((l >> 4) << 2);
#pragma unroll
    for (int n = 0; n < 4; ++n) {
      int cg = b0 + wc * 64 + n * 16 + (l & 15);
#pragma unroll
      for (int r = 0; r < 4; ++r)
        atomicAdd(S + (size_t)(rg + r) * F + cg, acc[m][n][r]);
    }
  }
}

// ---------------- K3: finalize mean + E = cov - I ----------------
__global__ __launch_bounds__(256) void k_finalize(const float* __restrict__ S,
                                                  const float* __restrict__ colsum,
                                                  float* __restrict__ mean,
                                                  float* __restrict__ E,
                                                  u16* __restrict__ Eb) {
  int gid = blockIdx.x * 256 + threadIdx.x;
  int i = gid >> 9, j = gid & 511;
  float si = 0.0f, sj = 0.0f;
#pragma unroll
  for (int bkt = 0; bkt < 8; ++bkt) {
    si += colsum[bkt * 512 + i];
    sj += colsum[bkt * 512 + j];
  }
  float mi = si * (1.0f / 65536.0f);
  float mj = sj * (1.0f / 65536.0f);
  float sv = ((i >> 7) <= (j >> 7)) ? S[(size_t)i * F + j] : S[(size_t)j * F + i];
  float cov = (sv - 65536.0f * mi * mj) * (1.0f / 65535.0f);
  float e = cov + ((i == j) ? (0.001f - 1.0f) : 0.0f);
  E[gid] = e;
  Eb[gid] = f2bf(e);
  if (gid < F) {
    float s = 0.0f;
#pragma unroll
    for (int bkt = 0; bkt < 8; ++bkt) s += colsum[bkt * 512 + gid];
    mean[gid] = s * (1.0f / 65536.0f);
  }
}

// ---------------- K4/K5: degree-4 Taylor of (I+E)^(-1/2) ----------------
__global__ __launch_bounds__(256) void k_poly(char* __restrict__ wsb, int stg) {
  __shared__ __attribute__((aligned(16))) u16 As[2][64 * 64];
  __shared__ __attribute__((aligned(16))) u16 Bs[2][64 * 64];
  const int tile = blockIdx.x;
  const int tr = tile >> 3, tc = tile & 7;
  const int r0 = tr * 64, c0 = tc * 64;
  const u16* Eb  = (const u16*)(wsb + WS_EB);
  const u16* E2b = (const u16*)(wsb + WS_E2B);
  const u16* Gb  = (const u16*)(wsb + WS_GB);
  const u16* Ab; const u16* Bb;
  if (stg == 0) { Ab = Eb;  Bb = Eb; }
  else          { Ab = E2b; Bb = Gb; }
  const int t = threadIdx.x;
  const int l = t & 63, w = t >> 6, wr = w >> 1, wc = w & 1;
  f32x4 acc[2][2] = {};
  stage64(As[0], Ab + (size_t)r0 * F, F, t);
  stage64(Bs[0], Bb + (size_t)c0 * F, F, t);
  __syncthreads();
  for (int it = 0; it < 8; ++it) {
    int cur = it & 1;
    if (it < 7) {
      stage64(As[cur ^ 1], Ab + (size_t)r0 * F + (it + 1) * 64, F, t);
      stage64(Bs[cur ^ 1], Bb + (size_t)c0 * F + (it + 1) * 64, F, t);
    }
    mm64(As[cur], Bs[cur], wr, wc, l, acc);
    __syncthreads();
  }
  const float* Ef  = (const float*)(wsb + WS_E);
  const float* E2f = (const float*)(wsb + WS_E2);
  const float* mean = (const float*)(wsb + WS_MEAN);
  float* tacc = (float*)(wsb + WS_TACC);
  const float c1 = -0.5f, c2 = 0.375f, c3 = -0.3125f, c4 = 35.0f / 128.0f;
#pragma unroll
  for (int n = 0; n < 2; ++n) {
    int cg = c0 + wc * 32 + n * 16 + (l & 15);
    float ts = 0.0f;
#pragma unroll
    for (int m = 0; m < 2; ++m) {
#pragma unroll
      for (int r = 0; r < 4; ++r) {
        int rg = r0 + wr * 32 + m * 16 + ((l >> 4) << 2) + r;
        size_t o = (size_t)rg * F + cg;
        float v = acc[m][n][r];
        if (stg == 0) {
          ((float*)(wsb + WS_E2))[o] = v;
          ((u16*)(wsb + WS_E2B))[o] = f2bf(v);
          ((u16*)(wsb + WS_GB))[o]  = f2bf(c3 * Ef[o] + c4 * v);
        } else {
          float wv = c1 * Ef[o] + c2 * E2f[o] + v + ((rg == cg) ? 1.0f : 0.0f);
          ((u16*)(wsb + WS_WB))[o] = f2bf(wv);
          ts += mean[rg] * wv;
        }
      }
    }
    if (stg == 1) atomicAdd(tacc + cg, ts);
  }
}

// ---------------- K6a: out = (xb@W - tacc)*w + b  (pure bf16 GEMM) --------
__global__ __launch_bounds__(512) void k_out_b(const u16* __restrict__ xb,
                                               const u16* __restrict__ Wb,
                                               const float* __restrict__ tacc,
                                               const float* __restrict__ wgt,
                                               const float* __restrict__ bias,
                                               float* __restrict__ out) {
  __shared__ __attribute__((aligned(16))) u16 As[2][128 * 64];
  __shared__ __attribute__((aligned(16))) u16 Bs[2][128 * 64];
  const int b = blockIdx.x;
  const int i = b >> 3;
  const int rt = (b & 7) * 64 + (i >> 2), ct = i & 3;
  const int i0 = rt * 128, j0 = ct * 128;
  const int t = threadIdx.x;
  const int l = t & 63, w = t >> 6, wr = w >> 2, wc = w & 3;
  f32x4 acc[4][2] = {};
  const u16* Abase = xb + (size_t)i0 * F;
  const u16* Bbase = Wb + (size_t)j0 * F;
  stage512(As[0], Abase, F, t);
  stage512(Bs[0], Bbase, F, t);
  __syncthreads();
  for (int it = 0; it < 8; ++it) {
    int cur = it & 1;
    if (it < 7) {
      stage512(As[cur ^ 1], Abase + (it + 1) * 64, F, t);
      stage512(Bs[cur ^ 1], Bbase + (it + 1) * 64, F, t);
    }
    mm_step8(As[cur], Bs[cur], wr, wc, l, acc);
    __syncthreads();
  }
#pragma unroll
  for (int n = 0; n < 2; ++n) {
    int cg = j0 + wc * 32 + n * 16 + (l & 15);
    float mv = tacc[cg];
    float wv = wgt[cg], bv = bias[cg];
#pragma unroll
    for (int m = 0; m < 4; ++m) {
      int rb = i0 + wr * 64 + m * 16 + ((l >> 4) << 2);
#pragma unroll
      for (int r = 0; r < 4; ++r) {
        size_t o = (size_t)(rb + r) * F + cg;
        __builtin_nontemporal_store((acc[m][n][r] - mv) * wv + bv, out + o);
      }
    }
  }
}

// ---------------- K6b: small-ws fallback (fp32 x reg-staged A) ----------------
__global__ __launch_bounds__(512) void k_out_f(const float* __restrict__ x,
                                               const u16* __restrict__ Wb,
                                               const float* __restrict__ tacc,
                                               const float* __restrict__ wgt,
                                               const float* __restrict__ bias,
                                               float* __restrict__ out) {
  __shared__ __attribute__((aligned(16))) u16 As[2][128 * 64];
  __shared__ __attribute__((aligned(16))) u16 Bs[2][128 * 64];
  const int b = blockIdx.x;
  const int i = b >> 3;
  const int rt = (b & 7) * 64 + (i >> 2), ct = i & 3;
  const int i0 = rt * 128, j0 = ct * 128;
  const int t = threadIdx.x;
  const int l = t & 63, w = t >> 6, wr = w >> 2, wc = w & 3;
  f32x4 acc[4][2] = {};
  float4 ld[4];
  stage512(Bs[0], Wb + (size_t)j0 * F, F, t);
#pragma unroll
  for (int q = 0; q < 4; ++q) {
    int idx = q * 512 + t, r = idx >> 4, kc = idx & 15;
    ld[q] = *(const float4*)(x + (size_t)(i0 + r) * F + kc * 4);
  }
#pragma unroll
  for (int q = 0; q < 4; ++q) {
    int idx = q * 512 + t, r = idx >> 4, kc = idx & 15;
    ushort4 o;
    o.x = f2bf(ld[q].x); o.y = f2bf(ld[q].y); o.z = f2bf(ld[q].z); o.w = f2bf(ld[q].w);
    *(ushort4*)(As[0] + r * 64 + (((kc >> 1) ^ (r & 7)) << 3) + ((kc & 1) << 2)) = o;
  }
  __syncthreads();
  for (int it = 0; it < 8; ++it) {
    int cur = it & 1;
    if (it < 7) {
      int kk = (it + 1) * 64;
#pragma unroll
      for (int q = 0; q < 4; ++q) {
        int idx = q * 512 + t, r = idx >> 4, kc = idx & 15;
        ld[q] = *(const float4*)(x + (size_t)(i0 + r) * F + kk + kc * 4);
      }
      stage512(Bs[cur ^ 1], Wb + (size_t)j0 * F + kk, F, t);
    }
    mm_step8(As[cur], Bs[cur], wr, wc, l, acc);
    if (it < 7) {
#pragma unroll
      for (int q = 0; q < 4; ++q) {
        int idx = q * 512 + t, r = idx >> 4, kc = idx & 15;
        ushort4 o;
        o.x = f2bf(ld[q].x); o.y = f2bf(ld[q].y); o.z = f2bf(ld[q].z); o.w = f2bf(ld[q].w);
        *(ushort4*)(As[cur ^ 1] + r * 64 + (((kc >> 1) ^ (r & 7)) << 3) + ((kc & 1) << 2)) = o;
      }
    }
    __syncthreads();
  }
#pragma unroll
  for (int n = 0; n < 2; ++n) {
    int cg = j0 + wc * 32 + n * 16 + (l & 15);
    float mv = tacc[cg];
    float wv = wgt[cg], bv = bias[cg];
#pragma unroll
    for (int m = 0; m < 4; ++m) {
      int rb = i0 + wr * 64 + m * 16 + ((l >> 4) << 2);
#pragma unroll
      for (int r = 0; r < 4; ++r) {
        size_t o = (size_t)(rb + r) * F + cg;
        __builtin_nontemporal_store((acc[m][n][r] - mv) * wv + bv, out + o);
      }
    }
  }
}

extern "C" void kernel_launch(void* const* d_in, const int* in_sizes, int n_in,
                              void* d_out, int out_size, void* d_ws, size_t ws_size,
                              hipStream_t stream) {
  (void)in_sizes; (void)n_in; (void)out_size;
  const float* x      = (const float*)d_in[0];
  const float* weight = (const float*)d_in[1];
  const float* bias   = (const float*)d_in[2];
  float* out = (float*)d_out;
  char* ws   = (char*)d_ws;
  // xbT (64 MiB) overlays d_out; only read by k_cov, dead before k_out writes.
  u16* xbT = (u16*)d_out;
  const bool big = ws_size >= (size_t)WS_NEED_BIG;
  u16* xb = big ? (u16*)(ws + WS_XB) : nullptr;

  float* S      = (float*)(ws + WS_S);
  float* colsum = (float*)(ws + WS_COLSUM);
  float* tacc   = (float*)(ws + WS_TACC);
  float* mean   = (float*)(ws + WS_MEAN);

  // zero S + colsum buckets + tacc (261 * 4096 B covers 1,067,008 B + slack
  // into mean, which finalize rewrites before reading)
  k_zero<<<dim3(261), dim3(256), 0, stream>>>((uint4*)ws);

  k_prep4<<<dim3(512, 8), dim3(256), 0, stream>>>(x, xbT, colsum, xb);
  k_cov<<<dim3(320), dim3(256), 0, stream>>>(xbT, S);
  k_finalize<<<dim3(1024), dim3(256), 0, stream>>>(S, colsum, mean,
                                                   (float*)(ws + WS_E),
                                                   (u16*)(ws + WS_EB));
  k_poly<<<dim3(64), dim3(256), 0, stream>>>(ws, 0);
  k_poly<<<dim3(64), dim3(256), 0, stream>>>(ws, 1);
  if (big) {
    k_out_b<<<dim3(2048), dim3(512), 0, stream>>>(xb, (u16*)(ws + WS_WB),
                                                  tacc, weight, bias, out);
  } else {
    k_out_f<<<dim3(2048), dim3(512), 0, stream>>>(x, (u16*)(ws + WS_WB),
                                                  tacc, weight, bias, out);
  }
}